// Round 1
// baseline (122.734 us; speedup 1.0000x reference)
//
#include <hip/hip_runtime.h>

typedef _Float16 half4 __attribute__((ext_vector_type(4)));
typedef float    f32x4 __attribute__((ext_vector_type(4)));
typedef int      i32x4 __attribute__((ext_vector_type(4)));

#define MFMA16(a,b,c) __builtin_amdgcn_mfma_f32_16x16x16f16((a),(b),(c),0,0,0)

static constexpr int N_NODES  = 200000;
static constexpr int N_GRAPHS = 64;

// ---- workspace byte offsets ----
static constexpr size_t WS_ZWT    = 0;        // [64][128][16] f16 : zW1^T per graph (d-major, k inner)
static constexpr size_t WS_W2T    = 262144;   // [128][128] f16    : W2T[d_out][d_in] = W2[d_in][d_out]
static constexpr size_t WS_WHT    = 294912;   // [16][128]  f16    : rows 0..3 = [Wp|Wv]^T, rows 4..15 zero
static constexpr size_t WS_GSTART = 299008;   // 65 int : first node of graph g (sorted batch)
static constexpr size_t WS_CG     = 299520;   // 65 int : prefix of ceil(count_g/16)
static constexpr size_t WS_GTAB   = 299792;   // up to 12800 × int4 {g, node_base, node_end, 0}

// ---------------- prep1: graph boundaries + W2T + WhT ----------------
__global__ void gnn_prep1(const int* __restrict__ batch,
                          const float* __restrict__ W2,
                          const float* __restrict__ Wp,
                          const float* __restrict__ Wv,
                          int* __restrict__ gstart,
                          _Float16* __restrict__ w2t,
                          _Float16* __restrict__ wht)
{
    const int b = blockIdx.x, t = threadIdx.x;
    if (b < 782) {
        const int i = b * 256 + t;
        if (i < N_NODES) {
            const int bi   = batch[i];
            const int prev = (i == 0) ? -1 : batch[i - 1];
            if (bi != prev)
                for (int g = prev + 1; g <= bi; ++g) gstart[g] = i;
            if (i == N_NODES - 1)
                for (int g = bi + 1; g <= N_GRAPHS; ++g) gstart[g] = N_NODES;
        }
    } else if (b < 846) {
        const int e  = (b - 782) * 256 + t;   // 0..16383
        const int n  = e >> 7, kk = e & 127;  // w2t[n][kk] = W2[kk][n]
        w2t[e] = (_Float16)W2[kk * 128 + n];
    } else {
        for (int r = 0; r < 8; ++r) {
            const int e = r * 256 + t;        // 0..2047
            const int j = e >> 7, d = e & 127;
            float v = 0.f;
            if (j < 2)      v = Wp[d * 2 + j];
            else if (j < 4) v = Wv[d * 2 + (j - 2)];
            wht[e] = (_Float16)v;
        }
    }
}

// ---------------- prep2: zW1^T (f16) + group prefix ----------------
__global__ void gnn_prep2(const float* __restrict__ z,
                          const float* __restrict__ W1,
                          const int* __restrict__ gstart,
                          _Float16* __restrict__ zwt,
                          int* __restrict__ Cg)
{
    const int b = blockIdx.x, d = threadIdx.x;
    if (b < 256) {
        const int g = b >> 2, kq = b & 3;          // 4 slots per block
        const float* zb = z + (g * 16 + kq * 4) * 128;
        float a0 = 0.f, a1 = 0.f, a2 = 0.f, a3 = 0.f;
        for (int c = 0; c < 128; ++c) {
            const float w = W1[c * 128 + d];       // coalesced over d
            a0 += zb[c] * w;
            a1 += zb[128 + c] * w;
            a2 += zb[256 + c] * w;
            a3 += zb[384 + c] * w;
        }
        half4 o; o[0] = (_Float16)a0; o[1] = (_Float16)a1; o[2] = (_Float16)a2; o[3] = (_Float16)a3;
        *(half4*)(zwt + (g * 128 + d) * 16 + kq * 4) = o;
    } else if (d == 0) {
        int c = 0; Cg[0] = 0;
        for (int g = 0; g < 64; ++g) {
            const int cnt = gstart[g + 1] - gstart[g];
            c += (cnt + 15) >> 4;
            Cg[g + 1] = c;
        }
    }
}

// ---------------- prep3: flat group table (kills per-iter binary search) ----------------
__global__ void gnn_prep3(const int* __restrict__ gstart,
                          const int* __restrict__ Cg,
                          i32x4* __restrict__ gtab)
{
    const int t = blockIdx.x * 256 + threadIdx.x;
    const int total = Cg[64];
    if (t >= total) return;
    int lo = 0, hi = 64;
    while (lo < hi) { const int mid = (lo + hi + 1) >> 1; if (Cg[mid] <= t) lo = mid; else hi = mid - 1; }
    i32x4 e;
    e[0] = lo;                                  // graph
    e[1] = gstart[lo] + ((t - Cg[lo]) << 4);    // node_base
    e[2] = gstart[lo + 1];                      // node_end
    e[3] = 0;
    gtab[t] = e;
}

__device__ inline float fast_tanh(float x) {
    x = fminf(fmaxf(x, -15.f), 15.f);
    const float e = __expf(2.f * x);
    return (e - 1.f) / (e + 1.f);
}

// ---------------- main: fused slot-sum + MLP + heads, zero LDS ----------------
// All GEMMs transposed so lane&15 = node column everywhere; 16x16x16 C-row-run (quad*4+reg)
// == next MFMA's B k-run (quad*4+i) -> register pass-through, no LDS round-trips.
__global__ __launch_bounds__(256, 2) void gnn_main(
    const float* __restrict__ s,
    const float* __restrict__ b1,
    const float* __restrict__ b2,
    const float* __restrict__ bp,
    const float* __restrict__ bv,
    const _Float16* __restrict__ zwt,
    const _Float16* __restrict__ w2t,
    const _Float16* __restrict__ wht,
    const i32x4* __restrict__ gtab,
    const int* __restrict__ Cg,
    float* __restrict__ out)
{
    const int lane = threadIdx.x & 63;
    const int n16  = lane & 15;
    const int quad = lane >> 4;
    const int wid  = blockIdx.x * 4 + (threadIdx.x >> 6);
    const int nw   = gridDim.x * 4;

    // persistent W2^T fragments: A2'[m=d_out][k=d_in], 64 frags = 128 VGPR
    half4 a2[8][8];
#pragma unroll
    for (int mt = 0; mt < 8; ++mt)
#pragma unroll
        for (int t = 0; t < 8; ++t)
            a2[mt][t] = *(const half4*)(w2t + (mt * 16 + n16) * 128 + t * 16 + quad * 4);

    // persistent head fragments: A3[m=j][k=d] (rows j>=4 are zero)
    half4 a3[8];
#pragma unroll
    for (int t = 0; t < 8; ++t)
        a3[t] = *(const half4*)(wht + n16 * 128 + t * 16 + quad * 4);

    const float bp0 = bp[0], bp1 = bp[1], bv0 = bv[0], bv1 = bv[1];
    const int total = Cg[64];

    for (int gi = wid; gi < total; gi += nw) {
        const i32x4 ge = gtab[gi];
        const int g = ge[0], base = ge[1], end = ge[2];
        const int node  = base + n16;
        const bool valid = node < end;

        // B1' frag: s^T[k=slot][n=node]; K=16 native, no padding
        half4 bs = {(_Float16)0.f, (_Float16)0.f, (_Float16)0.f, (_Float16)0.f};
        if (valid) {
            const f32x4 sv = *(const f32x4*)(s + node * 16 + quad * 4);
            bs[0] = (_Float16)sv[0]; bs[1] = (_Float16)sv[1];
            bs[2] = (_Float16)sv[2]; bs[3] = (_Float16)sv[3];
        }

        // GEMM1': node_feat^T = zW1^T @ s^T  (8 MFMAs)
        const _Float16* zg = zwt + g * 2048;
        f32x4 acc1[8];
#pragma unroll
        for (int mt = 0; mt < 8; ++mt) {
            const half4 a1 = *(const half4*)(zg + (mt * 16 + n16) * 16 + quad * 4);
            const f32x4 zc = {0.f, 0.f, 0.f, 0.f};
            acc1[mt] = MFMA16(a1, bs, zc);
        }

        // h1 = relu(node_feat + b1) -> becomes B2' frags directly (register pass-through)
        half4 h1[8];
#pragma unroll
        for (int mt = 0; mt < 8; ++mt) {
            const f32x4 bb = *(const f32x4*)(b1 + mt * 16 + quad * 4);
#pragma unroll
            for (int i = 0; i < 4; ++i) {
                const float x = fmaxf(acc1[mt][i] + bb[i], 0.f);
                h1[mt][i] = (_Float16)x;
            }
        }

        // GEMM2' (64 MFMAs) fused with head (8 MFMAs); h2 frags are transient registers
        f32x4 acc3 = {0.f, 0.f, 0.f, 0.f};
#pragma unroll
        for (int mo = 0; mo < 8; ++mo) {
            f32x4 acc2 = {0.f, 0.f, 0.f, 0.f};
#pragma unroll
            for (int t = 0; t < 8; ++t)
                acc2 = MFMA16(a2[mo][t], h1[t], acc2);
            const f32x4 bb = *(const f32x4*)(b2 + mo * 16 + quad * 4);
            half4 h2;
#pragma unroll
            for (int i = 0; i < 4; ++i) {
                const float x = fmaxf(acc2[i] + bb[i], 0.f);
                h2[i] = (_Float16)x;
            }
            acc3 = MFMA16(a3[mo], h2, acc3);
        }

        // head output: lane = node col, quad0 regs = rows j=0..3 -> one dwordx4 per node
        if (quad == 0 && valid) {
            f32x4 o;
            o[0] = fast_tanh(acc3[0] + bp0);
            o[1] = fast_tanh(acc3[1] + bp1);
            o[2] = acc3[2] + bv0;
            o[3] = acc3[3] + bv1;
            *(f32x4*)(out + node * 4) = o;
        }
    }
}

extern "C" void kernel_launch(void* const* d_in, const int* in_sizes, int n_in,
                              void* d_out, int out_size, void* d_ws, size_t ws_size,
                              hipStream_t stream)
{
    const float* z     = (const float*)d_in[0];
    const float* s     = (const float*)d_in[1];
    const int*   batch = (const int*)d_in[2];
    const float* W1    = (const float*)d_in[3];
    const float* b1    = (const float*)d_in[4];
    const float* W2    = (const float*)d_in[5];
    const float* b2    = (const float*)d_in[6];
    const float* Wp    = (const float*)d_in[7];
    const float* bp    = (const float*)d_in[8];
    const float* Wv    = (const float*)d_in[9];
    const float* bv    = (const float*)d_in[10];
    float* out = (float*)d_out;

    char* w = (char*)d_ws;
    _Float16* zwt  = (_Float16*)(w + WS_ZWT);
    _Float16* w2t  = (_Float16*)(w + WS_W2T);
    _Float16* wht  = (_Float16*)(w + WS_WHT);
    int* gstart    = (int*)(w + WS_GSTART);
    int* Cg        = (int*)(w + WS_CG);
    i32x4* gtab    = (i32x4*)(w + WS_GTAB);

    hipLaunchKernelGGL(gnn_prep1, dim3(847), dim3(256), 0, stream,
                       batch, W2, Wp, Wv, gstart, w2t, wht);
    hipLaunchKernelGGL(gnn_prep2, dim3(257), dim3(128), 0, stream,
                       z, W1, gstart, zwt, Cg);
    hipLaunchKernelGGL(gnn_prep3, dim3(50), dim3(256), 0, stream,
                       gstart, Cg, gtab);
    hipLaunchKernelGGL(gnn_main, dim3(512), dim3(256), 0, stream,
                       s, b1, b2, bp, bv, zwt, w2t, wht, gtab, Cg, out);
}